// Round 3
// baseline (82.561 us; speedup 1.0000x reference)
//
#include <hip/hip_runtime.h>
#include <hip/hip_bf16.h>
#include <math.h>

// Ag3LESModel: N=3 atoms, n_rbf=16, n_hidden=32.
// Two MLPs (charge, short-range): 16 -> 32 (SiLU) -> 32 (SiLU) -> 1.
// latent_q = raw_q + (charge_state - sum(raw_q))/3
// E_lr = sum over pairs q_i*q_j/|p_i-p_j| ; E_sr = sum sr_mlp(features)
// Output (fp32, 4 elems): [E_lr+E_sr, q0, q1, q2]
//
// Dtype forensics (rounds 0-2):
//  - inputs: fp32 storage, values bf16-rounded by the harness
//    (bf16 reads -> NaN from mantissa-half decode; probe low-16-bits == 0).
//  - output: fp32 storage. Round 2 wrote packed bf16 and actual[0] came back
//    == q0 (the bf16 value landing in the high half of float word 0), error
//    |q0 - E| = 0.0908 -- the quantitative smoking gun.
// We keep the runtime input-dtype probe (block-uniform, no OOB on either
// interpretation) and store fp32.

__device__ __forceinline__ float silu(float x) {
    return x / (1.0f + __expf(-x));
}

template <typename T>
__device__ __forceinline__ float ldf(const void* p, int i);
template <>
__device__ __forceinline__ float ldf<float>(const void* p, int i) {
    return ((const float*)p)[i];
}
template <>
__device__ __forceinline__ float ldf<__hip_bfloat16>(const void* p, int i) {
    return __bfloat162float(((const __hip_bfloat16*)p)[i]);
}

struct Smem {
    float h1[2][3][32];
    float h2[2][3][32];
    float head[2][3];
};

template <typename T>
__device__ void body(const void* features, const void* positions,
                     const void* cw1, const void* cb1,
                     const void* cw2, const void* cb2,
                     const void* cw3, const void* cb3,
                     const void* sw1, const void* sb1,
                     const void* sw2, const void* sb2,
                     const void* sw3, const void* sb3,
                     float cs, float* out, Smem& s)
{
    const int t = threadIdx.x;        // 0..191
    const int m = t / 96;             // 0 = charge mlp, 1 = short-range mlp
    const int a = (t % 96) / 32;      // atom 0..2
    const int j = t % 32;             // hidden neuron 0..31

    const void* w1 = m ? sw1 : cw1;
    const void* b1 = m ? sb1 : cb1;
    const void* w2 = m ? sw2 : cw2;
    const void* b2 = m ? sb2 : cb2;

    // ---- layer 1: (16 -> 32) + SiLU ----
    {
        float acc = ldf<T>(b1, j);
#pragma unroll
        for (int k = 0; k < 16; ++k)
            acc = fmaf(ldf<T>(features, a * 16 + k), ldf<T>(w1, k * 32 + j), acc);
        s.h1[m][a][j] = silu(acc);
    }
    __syncthreads();

    // ---- layer 2: (32 -> 32) + SiLU ----
    {
        float acc = ldf<T>(b2, j);
#pragma unroll
        for (int k = 0; k < 32; ++k)
            acc = fmaf(s.h1[m][a][k], ldf<T>(w2, k * 32 + j), acc);
        s.h2[m][a][j] = silu(acc);
    }
    __syncthreads();

    // ---- layer 3: (32 -> 1), 6 dot products, one thread each ----
    if (j == 0) {
        const void* w3 = m ? sw3 : cw3;
        float acc = ldf<T>(m ? sb3 : cb3, 0);
#pragma unroll
        for (int k = 0; k < 32; ++k)
            acc = fmaf(s.h2[m][a][k], ldf<T>(w3, k), acc);
        s.head[m][a] = acc;
    }
    __syncthreads();

    // ---- epilogue: charge correction, Coulomb pairs, E_sr, store ----
    if (t == 0) {
        float q0 = s.head[0][0], q1 = s.head[0][1], q2 = s.head[0][2];
        const float corr = (cs - (q0 + q1 + q2)) * (1.0f / 3.0f);
        q0 += corr; q1 += corr; q2 += corr;

        float p[9];
#pragma unroll
        for (int i = 0; i < 9; ++i) p[i] = ldf<T>(positions, i);

        float E_lr = 0.0f;
        {   // pair (0,1)
            float dx = p[0] - p[3], dy = p[1] - p[4], dz = p[2] - p[5];
            E_lr += q0 * q1 / sqrtf(dx * dx + dy * dy + dz * dz);
        }
        {   // pair (0,2)
            float dx = p[0] - p[6], dy = p[1] - p[7], dz = p[2] - p[8];
            E_lr += q0 * q2 / sqrtf(dx * dx + dy * dy + dz * dz);
        }
        {   // pair (1,2)
            float dx = p[3] - p[6], dy = p[4] - p[7], dz = p[5] - p[8];
            E_lr += q1 * q2 / sqrtf(dx * dx + dy * dy + dz * dz);
        }

        const float E_sr = s.head[1][0] + s.head[1][1] + s.head[1][2];

        out[0] = E_lr + E_sr;   // fp32 output
        out[1] = q0;
        out[2] = q1;
        out[3] = q2;
    }
}

__global__ void __launch_bounds__(192)
ag3_les_kernel(const void* features, const void* positions,
               const void* cw1, const void* cb1,
               const void* cw2, const void* cb2,
               const void* cw3, const void* cb3,
               const void* sw1, const void* sb1,
               const void* sw2, const void* sb2,
               const void* sw3, const void* sb3,
               const int* charge_state, float* out)
{
    __shared__ Smem s;

    // ---- input dtype probe on `features` ----
    // First 24 words = 96 bytes: in-bounds whether the buffer is
    // 48 fp32 (192 B) or 48 bf16 (96 B). Low 16 bits of each word decode as
    // bf16: ~N(0,1) magnitudes if packed bf16; zeros (bf16-rounded fp32) or
    // uniform mantissa garbage if fp32.
    const unsigned* fw = (const unsigned*)features;
    int cnt = 0;
#pragma unroll
    for (int i = 0; i < 24; ++i) {
        float v = __uint_as_float((fw[i] & 0xFFFFu) << 16);
        float av = fabsf(v);
        if (av >= 0.015625f && av <= 8.0f) ++cnt;
    }
    const bool is_bf16 = (cnt >= 12);   // block-uniform

    // charge_state: small integer expected; fall back to float bits.
    float cs;
    {
        int ci = charge_state[0];
        if (ci >= -1000 && ci <= 1000) cs = (float)ci;
        else cs = __int_as_float(ci);
    }

    if (is_bf16)
        body<__hip_bfloat16>(features, positions, cw1, cb1, cw2, cb2, cw3, cb3,
                             sw1, sb1, sw2, sb2, sw3, sb3, cs, out, s);
    else
        body<float>(features, positions, cw1, cb1, cw2, cb2, cw3, cb3,
                    sw1, sb1, sw2, sb2, sw3, sb3, cs, out, s);
}

extern "C" void kernel_launch(void* const* d_in, const int* in_sizes, int n_in,
                              void* d_out, int out_size, void* d_ws, size_t ws_size,
                              hipStream_t stream) {
    ag3_les_kernel<<<1, 192, 0, stream>>>(
        d_in[0], d_in[1],
        d_in[2], d_in[3], d_in[4], d_in[5], d_in[6], d_in[7],
        d_in[8], d_in[9], d_in[10], d_in[11], d_in[12], d_in[13],
        (const int*)d_in[14], (float*)d_out);
}